// Round 1
// baseline (2810.921 us; speedup 1.0000x reference)
//
#include <hip/hip_runtime.h>
#include <hip/hip_bf16.h>

#define T_TOK 8192
#define DMODEL 2048
#define FDIM 8192
#define NEXP 8
#define CAP 2048

typedef __attribute__((ext_vector_type(8))) short bf16x8;
typedef __attribute__((ext_vector_type(4))) float f32x4;
typedef __attribute__((ext_vector_type(4))) unsigned short u16x4;

__device__ __forceinline__ unsigned short f2bf(float x) {
    unsigned u = __builtin_bit_cast(unsigned, x);
    return (unsigned short)((u + 0x7FFFu + ((u >> 16) & 1u)) >> 16);
}

__device__ __forceinline__ void gload_lds16(const void* g, void* l) {
    __builtin_amdgcn_global_load_lds(
        (const __attribute__((address_space(1))) unsigned int*)g,
        (__attribute__((address_space(3))) unsigned int*)l,
        16, 0, 0);
}

// ---------------- cast + transpose: in [R][Cc] f32  ->  out [Cc][R] bf16 ----------------
__global__ void __launch_bounds__(256) transcast(const float* __restrict__ in,
                                                 short* __restrict__ outT,
                                                 int R, int Cc, int e_base) {
    __shared__ __attribute__((aligned(16))) unsigned short tile[64][72];
    const int z = blockIdx.z;
    const int col0 = blockIdx.x * 64;
    const int row0 = blockIdx.y * 64;
    const float* I = in + (size_t)(e_base + z) * R * Cc;
    short* O = outT + (size_t)z * R * Cc;
    const int t = threadIdx.x;
    const int rl = t >> 4;
    const int c4 = (t & 15) << 2;
#pragma unroll
    for (int i = 0; i < 4; i++) {
        const int r = rl + (i << 4);
        float4 v = *(const float4*)(I + (size_t)(row0 + r) * Cc + (col0 + c4));
        u16x4 s;
        s[0] = f2bf(v.x); s[1] = f2bf(v.y); s[2] = f2bf(v.z); s[3] = f2bf(v.w);
        *(u16x4*)&tile[r][c4] = s;
    }
    __syncthreads();
    const int n = t >> 2;
    const int r0 = (t & 3) << 4;
    bf16x8 p0, p1;
#pragma unroll
    for (int j = 0; j < 8; j++) {
        p0[j] = (short)tile[r0 + j][n];
        p1[j] = (short)tile[r0 + 8 + j][n];
    }
    short* dst = O + (size_t)(col0 + n) * R + row0 + r0;
    *(bf16x8*)dst = p0;
    *(bf16x8*)(dst + 8) = p1;
}

// ---------------- gather tokens -> bf16 [nE][CAP][DMODEL] ----------------
__global__ void __launch_bounds__(256) gather_tok(const float* __restrict__ inputs,
                                                  const int* __restrict__ idx,
                                                  short* __restrict__ tok, int e_base) {
    const int c = blockIdx.x, es = blockIdx.y;
    const int tkn = idx[c * NEXP + e_base + es];
    const float* src = inputs + (size_t)tkn * DMODEL;
    short* dst = tok + ((size_t)es * CAP + c) * DMODEL;
    const int d0 = threadIdx.x << 3;
    float4 v0 = *(const float4*)(src + d0);
    float4 v1 = *(const float4*)(src + d0 + 4);
    bf16x8 o;
    o[0] = (short)f2bf(v0.x); o[1] = (short)f2bf(v0.y);
    o[2] = (short)f2bf(v0.z); o[3] = (short)f2bf(v0.w);
    o[4] = (short)f2bf(v1.x); o[5] = (short)f2bf(v1.y);
    o[6] = (short)f2bf(v1.z); o[7] = (short)f2bf(v1.w);
    *(bf16x8*)(dst + d0) = o;
}

// ---------------- m97-style GEMM core: A [M][K] bf16, Bt [N][K] bf16, 128x128 tile ------
__device__ __forceinline__ void gemm_tile(const short* __restrict__ A,
                                          const short* __restrict__ Bt,
                                          int K, int m0, int n0,
                                          short* As, short* Bs, f32x4 acc[4][4]) {
    const int tid = threadIdx.x;
    const int lane = tid & 63;
    const int w = tid >> 6;
    const int sRow = lane >> 3;        // 0..7
    const int sCol = (lane & 7) << 3;  // element offset (8 bf16 = 16B per lane)
    const short* aSrc[4];
    const short* bSrc[4];
#pragma unroll
    for (int i = 0; i < 4; i++) {
        const int chunk = (w << 2) + i;              // 0..15 -> 8 rows each
        aSrc[i] = A + (size_t)(m0 + (chunk << 3) + sRow) * K + sCol;
        bSrc[i] = Bt + (size_t)(n0 + (chunk << 3) + sRow) * K + sCol;
    }
#pragma unroll
    for (int mt = 0; mt < 4; mt++)
#pragma unroll
        for (int nt = 0; nt < 4; nt++)
            acc[mt][nt] = (f32x4){0.f, 0.f, 0.f, 0.f};

    const int wm = (w & 1) << 6;
    const int wn = (w >> 1) << 6;
    const short* aRd = As + ((wm + (lane & 15)) << 6) + ((lane >> 4) << 3);
    const short* bRd = Bs + ((wn + (lane & 15)) << 6) + ((lane >> 4) << 3);

    for (int kt = 0; kt < K; kt += 64) {
        __syncthreads();
#pragma unroll
        for (int i = 0; i < 4; i++) {
            const int chunk = (w << 2) + i;
            gload_lds16(aSrc[i], (char*)As + (chunk << 10));
            gload_lds16(bSrc[i], (char*)Bs + (chunk << 10));
            aSrc[i] += 64;
            bSrc[i] += 64;
        }
        __builtin_amdgcn_s_waitcnt(0);
        __syncthreads();
#pragma unroll
        for (int kk = 0; kk < 2; kk++) {
            bf16x8 af[4], bfr[4];
#pragma unroll
            for (int mt = 0; mt < 4; mt++) af[mt] = *(const bf16x8*)(aRd + (mt << 10) + (kk << 5));
#pragma unroll
            for (int nt = 0; nt < 4; nt++) bfr[nt] = *(const bf16x8*)(bRd + (nt << 10) + (kk << 5));
#pragma unroll
            for (int mt = 0; mt < 4; mt++)
#pragma unroll
                for (int nt = 0; nt < 4; nt++)
                    acc[mt][nt] = __builtin_amdgcn_mfma_f32_16x16x32_bf16(
                        af[mt], bfr[nt], acc[mt][nt], 0, 0, 0);
        }
    }
}

// ---------------- GEMM1: h = gelu(tok @ W1 + b1), h bf16 [nE][CAP][FDIM] ----------------
__global__ void __launch_bounds__(256) gemm1_kernel(const short* __restrict__ tok,
                                                    const short* __restrict__ w1t,
                                                    const float* __restrict__ b1,
                                                    short* __restrict__ h, int e_base) {
    __shared__ __attribute__((aligned(16))) short As[128 * 64];
    __shared__ __attribute__((aligned(16))) short Bs[128 * 64];
    const int z = blockIdx.z;
    const int e = e_base + z;
    const int m0 = blockIdx.y * 128;
    const int n0 = blockIdx.x * 128;
    const short* A = tok + (size_t)z * CAP * DMODEL;
    const short* Bt = w1t + (size_t)z * FDIM * DMODEL;
    f32x4 acc[4][4];
    gemm_tile(A, Bt, DMODEL, m0, n0, As, Bs, acc);

    const int lane = threadIdx.x & 63;
    const int w = threadIdx.x >> 6;
    const int wm = (w & 1) << 6, wn = (w >> 1) << 6;
    const int col = lane & 15, quad = lane >> 4;
    short* H = h + (size_t)z * CAP * FDIM;
    const float* b1e = b1 + (size_t)e * FDIM;
    float bias[4];
#pragma unroll
    for (int nt = 0; nt < 4; nt++) bias[nt] = b1e[n0 + wn + nt * 16 + col];
#pragma unroll
    for (int mt = 0; mt < 4; mt++) {
#pragma unroll
        for (int i = 0; i < 4; i++) {
            const int m = m0 + wm + mt * 16 + quad * 4 + i;
            short* hrow = H + (size_t)m * FDIM;
#pragma unroll
            for (int nt = 0; nt < 4; nt++) {
                float v = acc[mt][nt][i] + bias[nt];
                // jax.nn.gelu approximate=True (tanh form), tanh via exp
                float zz = 0.7978845608028654f * (v + 0.044715f * v * v * v);
                float ex = __expf(2.0f * zz);
                float th = 1.0f - 2.0f * __builtin_amdgcn_rcpf(ex + 1.0f);
                float g = 0.5f * v * (1.0f + th);
                hrow[n0 + wn + nt * 16 + col] = (short)f2bf(g);
            }
        }
    }
}

// ---------------- GEMM2: out_ce = h @ W2 + b2; scatter-add (out_ce * w) -----------------
__global__ void __launch_bounds__(256) gemm2_kernel(const short* __restrict__ h,
                                                    const short* __restrict__ w2t,
                                                    const float* __restrict__ b2,
                                                    const float* __restrict__ inw,
                                                    const int* __restrict__ idx,
                                                    float* __restrict__ out, int e_base) {
    __shared__ __attribute__((aligned(16))) short As[128 * 64];
    __shared__ __attribute__((aligned(16))) short Bs[128 * 64];
    const int z = blockIdx.z;
    const int e = e_base + z;
    const int m0 = blockIdx.y * 128;
    const int n0 = blockIdx.x * 128;
    const short* A = h + (size_t)z * CAP * FDIM;
    const short* Bt = w2t + (size_t)z * DMODEL * FDIM;
    f32x4 acc[4][4];
    gemm_tile(A, Bt, FDIM, m0, n0, As, Bs, acc);

    const int lane = threadIdx.x & 63;
    const int w = threadIdx.x >> 6;
    const int wm = (w & 1) << 6, wn = (w >> 1) << 6;
    const int col = lane & 15, quad = lane >> 4;
    const float* b2e = b2 + (size_t)e * DMODEL;
    float bias[4];
#pragma unroll
    for (int nt = 0; nt < 4; nt++) bias[nt] = b2e[n0 + wn + nt * 16 + col];
#pragma unroll
    for (int mt = 0; mt < 4; mt++) {
#pragma unroll
        for (int i = 0; i < 4; i++) {
            const int c = m0 + wm + mt * 16 + quad * 4 + i;
            const int tk = idx[c * NEXP + e];
            const float wt = inw[(size_t)tk * NEXP + e];
            float* orow = out + (size_t)tk * DMODEL;
#pragma unroll
            for (int nt = 0; nt < 4; nt++) {
                float v = (acc[mt][nt][i] + bias[nt]) * wt;
                unsafeAtomicAdd(orow + n0 + wn + nt * 16 + col, v);
            }
        }
    }
}

extern "C" void kernel_launch(void* const* d_in, const int* in_sizes, int n_in,
                              void* d_out, int out_size, void* d_ws, size_t ws_size,
                              hipStream_t stream) {
    const float* inputs = (const float*)d_in[0];
    const float* inw    = (const float*)d_in[1];
    const int*   idx    = (const int*)d_in[2];
    const float* W1     = (const float*)d_in[3];
    const float* b1     = (const float*)d_in[4];
    const float* W2     = (const float*)d_in[5];
    const float* b2     = (const float*)d_in[6];
    float* out = (float*)d_out;

    hipMemsetAsync(out, 0, (size_t)out_size * sizeof(float), stream);

    const size_t sW1T = (size_t)FDIM * DMODEL * 2;   // 32 MiB per expert
    const size_t sW2T = (size_t)DMODEL * FDIM * 2;   // 32 MiB per expert
    const size_t sTok = (size_t)CAP * DMODEL * 2;    // 8 MiB per expert
    const size_t sH   = (size_t)CAP * FDIM * 2;      // 32 MiB per expert
    char* p = (char*)d_ws;

    if (ws_size >= (sW1T + sW2T + sTok + sH) * NEXP) {
        short* w1t = (short*)p; p += sW1T * NEXP;
        short* w2t = (short*)p; p += sW2T * NEXP;
        short* tok = (short*)p; p += sTok * NEXP;
        short* h   = (short*)p;
        transcast<<<dim3(FDIM / 64, DMODEL / 64, NEXP), 256, 0, stream>>>(W1, w1t, DMODEL, FDIM, 0);
        gather_tok<<<dim3(CAP, NEXP), 256, 0, stream>>>(inputs, idx, tok, 0);
        gemm1_kernel<<<dim3(FDIM / 128, CAP / 128, NEXP), 256, 0, stream>>>(tok, w1t, b1, h, 0);
        transcast<<<dim3(DMODEL / 64, FDIM / 64, NEXP), 256, 0, stream>>>(W2, w2t, FDIM, DMODEL, 0);
        gemm2_kernel<<<dim3(DMODEL / 128, CAP / 128, NEXP), 256, 0, stream>>>(h, w2t, b2, inw, idx, out, 0);
    } else {
        // per-expert fallback, reuse one 104 MiB slot set
        short* w1t = (short*)p; p += sW1T;
        short* w2t = (short*)p; p += sW2T;
        short* tok = (short*)p; p += sTok;
        short* h   = (short*)p;
        for (int e = 0; e < NEXP; e++) {
            transcast<<<dim3(FDIM / 64, DMODEL / 64, 1), 256, 0, stream>>>(W1, w1t, DMODEL, FDIM, e);
            transcast<<<dim3(DMODEL / 64, FDIM / 64, 1), 256, 0, stream>>>(W2, w2t, FDIM, DMODEL, e);
            gather_tok<<<dim3(CAP, 1), 256, 0, stream>>>(inputs, idx, tok, e);
            gemm1_kernel<<<dim3(FDIM / 128, CAP / 128, 1), 256, 0, stream>>>(tok, w1t, b1, h, e);
            gemm2_kernel<<<dim3(DMODEL / 128, CAP / 128, 1), 256, 0, stream>>>(h, w2t, b2, inw, idx, out, e);
        }
    }
}